// Round 16
// baseline (470.892 us; speedup 1.0000x reference)
//
#include <hip/hip_runtime.h>
#include <hip/hip_bf16.h>

// GAT layer: N=50000 nodes, E=1.6M edges, DIN_N=128, DIN_E=64, DOUT_N=DOUT_E=64.
//   Wp = W1@W_fc, Wq = W3@W_fc                           (k0, 64x128 each, bf16)
//   z = x@W_fc.T; p = x@Wp.T + b; q = x@Wq.T             (k12, one MFMA GEMM, bf16 out;
//                                                         also zeroes deg)
//   feat[e] = lrelu([ef | p[src] | q[dst]] @ [W2; I; I])  (K3, K=192 MFMA,
//                         identity-B frags do the A->C transpose of p/q)
//   a = lrelu(lrelu(feat . wc)); ex = exp(a);
//   rank[e] = deg[dst]++  (atomic return value)           (K3)
//   off = exscan(deg)  (scan1/2/3)
//   pairs[off[dst]+rank[e]] = {src, ex}                   (scatter, NO atomics)
//   h[n] = sum(ex * z_bf[src]) / sum(ex)                  (K5, wave/node)
// Segment-max skipped: a is O(+-4) so exp cannot overflow; alpha identical.
// R15->R16: k3 ef staging single-buffered (4KB/wave) -> block LDS 40->24KB ->
// 6 blocks/CU = 24 waves (was 16). Per-tile vmcnt(16) (19 newer vmem ops
// after each stage; margin 3). TLP replaces the double-buffer ILP (m114).
// deg memset folded into k12.

typedef __attribute__((ext_vector_type(8))) short short8;
typedef __attribute__((ext_vector_type(4))) float f32x4;
typedef __attribute__((ext_vector_type(2))) int i32x2;

__device__ __forceinline__ short bf1(float f) {
    union { __hip_bfloat16 h; short s; } u;
    u.h = __float2bfloat16(f);          // compiler emits v_cvt_pk_bf16_f32 pairs
    return u.s;
}

__device__ __forceinline__ float bf2f(unsigned short u) {
    union { unsigned v; float f; } w; w.v = ((unsigned)u) << 16; return w.f;
}

__device__ __forceinline__ short8 pack8(f32x4 a, f32x4 b) {
    short8 r;
    r[0] = bf1(a[0]); r[1] = bf1(a[1]); r[2] = bf1(a[2]); r[3] = bf1(a[3]);
    r[4] = bf1(b[0]); r[5] = bf1(b[1]); r[6] = bf1(b[2]); r[7] = bf1(b[3]);
    return r;
}

__device__ __forceinline__ f32x4 ntld4(const float* p) {
    return __builtin_nontemporal_load((const f32x4*)p);
}

__device__ __forceinline__ f32x4 ld4(const float* p) {
    return *(const f32x4*)p;
}

#define MFMA16(A, B, C) __builtin_amdgcn_mfma_f32_16x16x32_bf16((A), (B), (C), 0, 0, 0)

// ---------------- k0: Wp = W1@W_fc, Wq = W3@W_fc (bf16 out) ----------------
__global__ __launch_bounds__(256) void k0_wpq(
    const float* __restrict__ W_edge, const float* __restrict__ W_fc,
    unsigned short* __restrict__ wp_bf, unsigned short* __restrict__ wq_bf)
{
    const int i = blockIdx.x * 256 + threadIdx.x;   // 0..8191
    if (i >= 64 * 128) return;
    const int c = i >> 7, k = i & 127;
    float sp = 0.f, sq = 0.f;
    for (int j = 0; j < 64; ++j) {
        const float f = W_fc[j * 128 + k];
        sp += W_edge[c * 192 + j] * f;
        sq += W_edge[c * 192 + 128 + j] * f;
    }
    wp_bf[i] = (unsigned short)bf1(sp);
    wq_bf[i] = (unsigned short)bf1(sq);
}

// ---------------- k12: z/p/q = x @ {W_fc,Wp,Wq}.T via MFMA; deg = 0 ---------
// C/D layout: col = lane&15, row = (lane>>4)*4 + reg (m89-verified).
__global__ __launch_bounds__(256) void k12_node(
    const float* __restrict__ nfeats, const float* __restrict__ W_fc,
    const unsigned short* __restrict__ wp_bf, const unsigned short* __restrict__ wq_bf,
    const float* __restrict__ b_edge,
    unsigned short* __restrict__ z_bf, unsigned short* __restrict__ p_bf,
    unsigned short* __restrict__ q_bf, int* __restrict__ deg, int ntiles)
{
    const int lane = threadIdx.x & 63;
    const int wave = threadIdx.x >> 6;
    const int l15 = lane & 15, g = lane >> 4;
    const int ti = blockIdx.x * 4 + wave;
    if (ti >= ntiles) return;
    const int n0 = ti * 16;

    if (lane < 16) deg[n0 + lane] = 0;   // replaces the memset launch

    // A fragments: 16 nodes x K=128 of nfeats (bf16)
    const float* xp = nfeats + (long)(n0 + l15) * 128 + g * 8;
    short8 Ax[4];
#pragma unroll
    for (int kt = 0; kt < 4; ++kt)
        Ax[kt] = pack8(ntld4(xp + kt * 32), ntld4(xp + kt * 32 + 4));

#pragma unroll
    for (int t = 0; t < 4; ++t) {
        const int col = t * 16 + l15;
        f32x4 az = (f32x4){0.f, 0.f, 0.f, 0.f};
        f32x4 ap = az, aq = az;
#pragma unroll
        for (int kt = 0; kt < 4; ++kt) {
            const float* bz = W_fc + (long)col * 128 + kt * 32 + g * 8;
            az = MFMA16(Ax[kt], pack8(ld4(bz), ld4(bz + 4)), az);
            const short8 bp = *(const short8*)(wp_bf + (long)col * 128 + kt * 32 + g * 8);
            ap = MFMA16(Ax[kt], bp, ap);
            const short8 bq = *(const short8*)(wq_bf + (long)col * 128 + kt * 32 + g * 8);
            aq = MFMA16(Ax[kt], bq, aq);
        }
        const float bias = b_edge[col];
#pragma unroll
        for (int r = 0; r < 4; ++r) {
            const long row = n0 + g * 4 + r;
            z_bf[row * 64 + col] = (unsigned short)bf1(az[r]);
            p_bf[row * 64 + col] = (unsigned short)bf1(ap[r] + bias);
            q_bf[row * 64 + col] = (unsigned short)bf1(aq[r]);
        }
    }
}

// ---------------- K3: per-edge K=192 MFMA + logits + deg/rank ----------------
// ef staged via global_load_lds into a SINGLE 4KB buffer per wave (24KB/block
// incl. W2f -> 6 blocks/CU). LDS granule (16B) L of a 4KB tile holds GLOBAL
// granule (L&~15) | ((L&15) ^ ((L>>4)&7)) -- source-side XOR swizzle so the
// stride-256B ds_read_b128 spreads across 8 bank groups.
// Per-tile: vmcnt(16) waits the stage issued last tile (19 newer vmem ops:
// 16 feat stores + exbuf + rank + atomicAdd; margin 3). lgkmcnt(0) orders
// this tile's ds_reads before the same-buffer restage.
// C/D layout (m89-verified): col = lane&15, row = (lane>>4)*4 + reg.
#define LOAD_PQ(T, PQ) {                                                    \
    const int sE_ = __shfl(((T) < 4) ? sAll0 : sAll1, ((T)&3) * 16 + l15, 64); \
    const int dE_ = __shfl(((T) < 4) ? dAll0 : dAll1, ((T)&3) * 16 + l15, 64); \
    const unsigned short* pp_ = p_bf + (long)sE_ * 64 + g * 8;              \
    PQ[0] = *(const short8*)pp_;                                            \
    PQ[1] = *(const short8*)(pp_ + 32);                                     \
    const unsigned short* qp_ = q_bf + (long)dE_ * 64 + g * 8;              \
    PQ[2] = *(const short8*)qp_;                                            \
    PQ[3] = *(const short8*)(qp_ + 32);                                     \
}

#define STAGE_EF(T) {                                                       \
    const float* gs_ = efeats + (wbase + (T) * 16) * 64;                    \
    _Pragma("unroll")                                                       \
    for (int i_ = 0; i_ < 4; ++i_) {                                        \
        const int L_ = i_ * 64 + lane;                                      \
        const int G_ = (L_ & ~15) | ((L_ & 15) ^ ((L_ >> 4) & 7));          \
        __builtin_amdgcn_global_load_lds(                                   \
            (const __attribute__((address_space(1))) unsigned int*)(gs_ + G_ * 4), \
            (__attribute__((address_space(3))) unsigned int*)(&efb[wave][i_ * 256]), \
            16, 0, 0);                                                      \
    }                                                                       \
}

#define EF_READ(E0, E1, E2, E3) {                                           \
    const float* eb2_ = &efb[wave][0];                                      \
    const int ro_ = l15 * 64, sx_ = l15 & 7;                                \
    E0 = *(const f32x4*)(eb2_ + ro_ + (((2 * g    ) ^ sx_) << 2));          \
    E1 = *(const f32x4*)(eb2_ + ro_ + (((2 * g + 1) ^ sx_) << 2));          \
    E2 = *(const f32x4*)(eb2_ + ro_ + (((2 * g + 8) ^ sx_) << 2));          \
    E3 = *(const f32x4*)(eb2_ + ro_ + (((2 * g + 9) ^ sx_) << 2));          \
}

#define VMW asm volatile("s_waitcnt vmcnt(16)" ::: "memory");

#define DO_TILE(T, PQ, DOWAIT, DOPQ, DOSTAGE) {                             \
    const long eb_ = wbase + (T) * 16;                                      \
    DOWAIT                                                                  \
    f32x4 e0_, e1_, e2_, e3_;                                               \
    EF_READ(e0_, e1_, e2_, e3_);                                            \
    DOPQ                                                                    \
    asm volatile("s_waitcnt lgkmcnt(0)" ::: "memory");                      \
    DOSTAGE                                                                 \
    f32x4 acc_[4];                                                          \
    _Pragma("unroll")                                                       \
    for (int t = 0; t < 4; ++t) acc_[t] = (f32x4){0.f, 0.f, 0.f, 0.f};      \
    acc_[0] = MFMA16(PQ[0], IdA, acc_[0]);                                  \
    acc_[1] = MFMA16(PQ[0], IdB, acc_[1]);                                  \
    acc_[2] = MFMA16(PQ[1], IdA, acc_[2]);                                  \
    acc_[3] = MFMA16(PQ[1], IdB, acc_[3]);                                  \
    acc_[0] = MFMA16(PQ[2], IdA, acc_[0]);                                  \
    acc_[1] = MFMA16(PQ[2], IdB, acc_[1]);                                  \
    acc_[2] = MFMA16(PQ[3], IdA, acc_[2]);                                  \
    acc_[3] = MFMA16(PQ[3], IdB, acc_[3]);                                  \
    short8 Aef0_ = pack8(e0_, e1_), Aef1_ = pack8(e2_, e3_);                \
    _Pragma("unroll")                                                       \
    for (int t = 0; t < 4; ++t) {                                           \
        acc_[t] = MFMA16(Aef0_, W2f[t * 64 + lane], acc_[t]);               \
        acc_[t] = MFMA16(Aef1_, W2f[(4 + t) * 64 + lane], acc_[t]);         \
    }                                                                       \
    float myex_ = 0.f;                                                      \
    _Pragma("unroll")                                                       \
    for (int r = 0; r < 4; ++r) {                                           \
        float s_ = 0.f;                                                     \
        _Pragma("unroll")                                                   \
        for (int t = 0; t < 4; ++t) {                                       \
            float v_ = acc_[t][r];                                          \
            v_ = (v_ >= 0.f) ? v_ : 0.01f * v_;                             \
            __builtin_nontemporal_store(v_,                                 \
                feat_out + (eb_ + g * 4 + r) * 64 + t * 16 + l15);          \
            s_ += v_ * wc[t];                                               \
        }                                                                   \
        s_ += __shfl_xor(s_, 1, 16);                                        \
        s_ += __shfl_xor(s_, 2, 16);                                        \
        s_ += __shfl_xor(s_, 4, 16);                                        \
        s_ += __shfl_xor(s_, 8, 16);                                        \
        s_ = (s_ >= 0.f) ? s_ : 0.01f * s_;                                 \
        s_ = (s_ >= 0.f) ? s_ : 0.01f * s_;                                 \
        const float ex_ = __expf(s_);                                       \
        if (l15 == r) myex_ = ex_;                                          \
    }                                                                       \
    const int dmine_ = __shfl(((T) < 4) ? dAll0 : dAll1,                    \
                              ((T)&3) * 16 + g * 4 + (l15 & 3), 64);        \
    if (l15 < 4) {                                                          \
        exbuf[eb_ + g * 4 + l15] = myex_;                                   \
        rank[eb_ + g * 4 + l15] = atomicAdd(&deg[dmine_], 1);               \
    }                                                                       \
}

__global__ __launch_bounds__(256, 6) void k3_edges(
    const float* __restrict__ efeats, const int* __restrict__ src,
    const int* __restrict__ dst, const float* __restrict__ W_edge,
    const float* __restrict__ w_coef, const unsigned short* __restrict__ p_bf,
    const unsigned short* __restrict__ q_bf, float* __restrict__ feat_out,
    float* __restrict__ exbuf, int* __restrict__ deg, int* __restrict__ rank)
{
    __shared__ short8 W2f[512];     // pre-packed W2 B-frags, 8KB
    __shared__ float efb[4][1024];  // [wave][4KB ef tile], 16KB -> 24KB total

    const int tid = threadIdx.x;
    const int lane = tid & 63;
    const int wave = tid >> 6;
    const int l15 = lane & 15, g = lane >> 4;
    const long wbase = ((long)blockIdx.x * 4 + wave) * 128;

    // stage tile 0 (drained by the __syncthreads below)
    STAGE_EF(0);
    const int sAll0 = src[wbase + lane];
    const int dAll0 = dst[wbase + lane];
    const int sAll1 = src[wbase + 64 + lane];
    const int dAll1 = dst[wbase + 64 + lane];

    // fill W2 fragment LDS: frag fi -> (s = fi>>6, l = fi&63)
#pragma unroll
    for (int jj = 0; jj < 2; ++jj) {
        const int fi = tid + jj * 256;
        const int s = fi >> 6, l = fi & 63;
        const int col = (s & 3) * 16 + (l & 15);
        const int gg = l >> 4, kt = s >> 2;
        const float* wp = W_edge + col * 192 + 64 + kt * 32 + gg * 8;
        W2f[fi] = pack8(ld4(wp), ld4(wp + 4));
    }

    float wc[4];
#pragma unroll
    for (int t = 0; t < 4; ++t) wc[t] = w_coef[t * 16 + l15];

    // identity B-fragments: one-hot at kc == col (mod 32 block)
    const short one = (short)0x3F80;   // bf16 1.0
    short8 IdA, IdB;
#pragma unroll
    for (int jj = 0; jj < 8; ++jj) {
        IdA[jj] = (l15 == g * 8 + jj) ? one : (short)0;        // cols 0..15 / 32..47
        IdB[jj] = (16 + l15 == g * 8 + jj) ? one : (short)0;   // cols 16..31 / 48..63
    }

    short8 pqA[4], pqB[4];
    LOAD_PQ(0, pqA);
    __syncthreads();   // W2f visible; vmcnt(0) drain => tile 0 staged, pqA ready

    DO_TILE(0, pqA, ,    { LOAD_PQ(1, pqB); }, { STAGE_EF(1); });
    DO_TILE(1, pqB, VMW, { LOAD_PQ(2, pqA); }, { STAGE_EF(2); });
    DO_TILE(2, pqA, VMW, { LOAD_PQ(3, pqB); }, { STAGE_EF(3); });
    DO_TILE(3, pqB, VMW, { LOAD_PQ(4, pqA); }, { STAGE_EF(4); });
    DO_TILE(4, pqA, VMW, { LOAD_PQ(5, pqB); }, { STAGE_EF(5); });
    DO_TILE(5, pqB, VMW, { LOAD_PQ(6, pqA); }, { STAGE_EF(6); });
    DO_TILE(6, pqA, VMW, { LOAD_PQ(7, pqB); }, { STAGE_EF(7); });
    DO_TILE(7, pqB, VMW, , );
}

// ---------------- scan1: per-block (1024 elems) totals ----------------
__global__ __launch_bounds__(256) void k_scan1(
    const int* __restrict__ deg, int* __restrict__ bsum, int N)
{
    __shared__ int ws4[4];
    const int tid = threadIdx.x, lane = tid & 63, wave = tid >> 6;
    const int i0 = blockIdx.x * 1024 + tid * 4;
    int s = 0;
#pragma unroll
    for (int jj = 0; jj < 4; ++jj) {
        const int i = i0 + jj;
        if (i < N) s += deg[i];
    }
#pragma unroll
    for (int d = 1; d < 64; d <<= 1) s += __shfl_xor(s, d, 64);
    if (lane == 0) ws4[wave] = s;
    __syncthreads();
    if (tid == 0) bsum[blockIdx.x] = ws4[0] + ws4[1] + ws4[2] + ws4[3];
}

// ---------------- scan2: scan of block totals (<=64 blocks) ----------------
__global__ __launch_bounds__(64) void k_scan2(
    const int* __restrict__ bsum, int* __restrict__ bpre,
    int* __restrict__ off, int nb, int N)
{
    const int t = threadIdx.x;
    const int v = (t < nb) ? bsum[t] : 0;
    int x = v;
#pragma unroll
    for (int d = 1; d < 64; d <<= 1) {
        int y = __shfl_up(x, d, 64);
        if (t >= d) x += y;
    }
    if (t < nb) bpre[t] = x - v;
    if (t == 63) off[N] = x;   // grand total == E
}

// ---------------- scan3: write off[i] ----------------
__global__ __launch_bounds__(256) void k_scan3(
    const int* __restrict__ deg, const int* __restrict__ bpre,
    int* __restrict__ off, int N)
{
    __shared__ int ws4[4];
    const int tid = threadIdx.x, lane = tid & 63, wave = tid >> 6;
    const int i0 = blockIdx.x * 1024 + tid * 4;
    int v[4];
#pragma unroll
    for (int jj = 0; jj < 4; ++jj) {
        const int i = i0 + jj;
        v[jj] = (i < N) ? deg[i] : 0;
    }
    const int s = v[0] + v[1] + v[2] + v[3];
    int x = s;
#pragma unroll
    for (int d = 1; d < 64; d <<= 1) {
        int y = __shfl_up(x, d, 64);
        if (lane >= d) x += y;
    }
    if (lane == 63) ws4[wave] = x;
    __syncthreads();
    int wpre = 0;
#pragma unroll
    for (int w = 0; w < 4; ++w) if (w < wave) wpre += ws4[w];
    int run = bpre[blockIdx.x] + wpre + (x - s);
#pragma unroll
    for (int jj = 0; jj < 4; ++jj) {
        const int i = i0 + jj;
        if (i < N) off[i] = run;
        run += v[jj];
    }
}

// ---------------- scatter (atomic-free): pairs[off[d]+rank[e]] = {src, ex} ----
__global__ __launch_bounds__(256) void k_scatter(
    const int* __restrict__ src, const int* __restrict__ dst,
    const float* __restrict__ exbuf, const int* __restrict__ off,
    const int* __restrict__ rank, i32x2* __restrict__ pairs, long E)
{
    const long e = (long)blockIdx.x * 256 + threadIdx.x;
    if (e >= E) return;
    const int d = dst[e];
    const int pos = off[d] + rank[e];
    i32x2 pr;
    pr[0] = src[e];
    pr[1] = __float_as_int(exbuf[e]);
    pairs[pos] = pr;
}

// ---------------- K5: h[n] = sum(ex*z[src]) / sum(ex) ----------------
// one wave per node; lane = channel; z gathered as bf16 (128B rows).
__global__ __launch_bounds__(256) void k5_aggregate(
    const int* __restrict__ off, const i32x2* __restrict__ pairs,
    const unsigned short* __restrict__ z_bf, float* __restrict__ h, int N)
{
    const int wave = threadIdx.x >> 6, lane = threadIdx.x & 63;
    const int n = blockIdx.x * 4 + wave;
    if (n >= N) return;
    const int beg = off[n], end = off[n + 1];
    float den = 0.f;
    float a0 = 0.f, a1 = 0.f, a2 = 0.f, a3 = 0.f;
    for (int base = beg; base < end; base += 64) {
        const int rem = end - base;
        i32x2 pr = (i32x2){0, 0};
        if (lane < rem) pr = __builtin_nontemporal_load(&pairs[base + lane]);
        const float ex = __int_as_float(pr[1]);
        float t = ex;
#pragma unroll
        for (int d = 1; d < 64; d <<= 1) t += __shfl_xor(t, d, 64);
        den += t;
        const int cnt = rem < 64 ? rem : 64;
        const int cnt4 = (cnt + 3) & ~3;
        for (int j = 0; j < cnt4; j += 4) {
            const int s0 = __shfl(pr[0], j, 64);
            const int s1 = __shfl(pr[0], j + 1, 64);
            const int s2 = __shfl(pr[0], j + 2, 64);
            const int s3 = __shfl(pr[0], j + 3, 64);
            const float e0 = __shfl(ex, j, 64);
            const float e1 = __shfl(ex, j + 1, 64);
            const float e2 = __shfl(ex, j + 2, 64);
            const float e3 = __shfl(ex, j + 3, 64);
            a0 = fmaf(e0, bf2f(z_bf[(long)s0 * 64 + lane]), a0);
            a1 = fmaf(e1, bf2f(z_bf[(long)s1 * 64 + lane]), a1);
            a2 = fmaf(e2, bf2f(z_bf[(long)s2 * 64 + lane]), a2);
            a3 = fmaf(e3, bf2f(z_bf[(long)s3 * 64 + lane]), a3);
        }
    }
    const float acc = (a0 + a1) + (a2 + a3);
    __builtin_nontemporal_store((end > beg) ? acc / den : 0.f,
                                h + (long)n * 64 + lane);
}

extern "C" void kernel_launch(void* const* d_in, const int* in_sizes, int n_in,
                              void* d_out, int out_size, void* d_ws, size_t ws_size,
                              hipStream_t stream) {
    const float* nfeats = (const float*)d_in[0];
    const float* efeats = (const float*)d_in[1];
    const int*   src    = (const int*)d_in[2];
    const int*   dst    = (const int*)d_in[3];
    const float* W_fc   = (const float*)d_in[4];
    const float* W_edge = (const float*)d_in[5];
    const float* b_edge = (const float*)d_in[6];
    const float* w_coef = (const float*)d_in[7];

    const int  N = in_sizes[0] / 128;   // 50000
    const long E = in_sizes[2];         // 1600000
    const int  nb = (N + 1023) / 1024;  // 49
    const int  ntiles = N / 16;         // 3125

    float* h    = (float*)d_out;                 // [N,64]
    float* feat = (float*)d_out + (long)N * 64;  // [E,64]

    unsigned short* z_bf   = (unsigned short*)d_ws;        // N*64 bf16
    unsigned short* p_bf   = z_bf + (long)N * 64;          // N*64 bf16
    unsigned short* q_bf   = p_bf + (long)N * 64;          // N*64 bf16
    unsigned short* wp_bf  = q_bf + (long)N * 64;          // 64*128
    unsigned short* wq_bf  = wp_bf + 64 * 128;             // 64*128
    float*          exbuf  = (float*)(wq_bf + 64 * 128);   // E
    int*            deg    = (int*)(exbuf + E);            // N
    int*            rank   = deg + N;                      // E
    int*            off    = rank + E;                     // N+2 (8B-align pairs)
    i32x2*          pairs  = (i32x2*)(off + N + 2);        // E
    int*            bsum   = (int*)(pairs + E);            // 64
    int*            bpre   = bsum + 64;                    // 64

    k0_wpq<<<32, 256, 0, stream>>>(W_edge, W_fc, wp_bf, wq_bf);
    k12_node<<<(ntiles + 3) / 4, 256, 0, stream>>>(nfeats, W_fc, wp_bf, wq_bf,
                                                   b_edge, z_bf, p_bf, q_bf,
                                                   deg, ntiles);
    k3_edges<<<(int)(E / 512), 256, 0, stream>>>(efeats, src, dst, W_edge, w_coef,
                                                 p_bf, q_bf, feat, exbuf, deg, rank);
    k_scan1<<<nb, 256, 0, stream>>>(deg, bsum, N);
    k_scan2<<<1, 64, 0, stream>>>(bsum, bpre, off, nb, N);
    k_scan3<<<nb, 256, 0, stream>>>(deg, bpre, off, N);
    k_scatter<<<(int)((E + 255) / 256), 256, 0, stream>>>(src, dst, exbuf, off,
                                                          rank, pairs, E);
    k5_aggregate<<<(N + 3) / 4, 256, 0, stream>>>(off, pairs, z_bf, h, N);
}

// Round 17
// 348.756 us; speedup vs baseline: 1.3502x; 1.3502x over previous
//
#include <hip/hip_runtime.h>
#include <hip/hip_bf16.h>

// GAT layer: N=50000 nodes, E=1.6M edges, DIN_N=128, DIN_E=64, DOUT_N=DOUT_E=64.
//   Wp = W1@W_fc, Wq = W3@W_fc                           (k0, 64x128 each, bf16)
//   z = x@W_fc.T; p = x@Wp.T + b; q = x@Wq.T             (k12, one MFMA GEMM, bf16 out;
//                                                         also zeroes deg)
//   feat[e] = lrelu([ef | p[src] | q[dst]] @ [W2; I; I])  (K3, K=192 MFMA,
//                         identity-B frags do the A->C transpose of p/q)
//   a = lrelu(lrelu(feat . wc)); ex = exp(a);
//   rank[e] = deg[dst]++  (atomic return value)           (K3)
//   off = exscan(deg)  (scan1/2/3)
//   pairs[off[dst]+rank[e]] = {src, ex}                   (scatter, NO atomics)
//   h[n] = sum(ex * z_bf[src]) / sum(ex)                  (K5, wave/node)
// Segment-max skipped: a is O(+-4) so exp cannot overflow; alpha identical.
// R16->R17: R16's single-buffer + (256,6) spilled AGAIN (VGPR 40, +240MB
// scratch round-trip). Full revert to the proven composite: R12-exact k3
// (dbuf, 40KB LDS, (256,4), vmcnt(40), 56 VGPR) + R15 rank-fused scatter +
// deg-memset folded into k12. k3's R12 schedule is the unique no-spill
// point (6 failed perturbations: R8/R10/R11/R13/R16).

typedef __attribute__((ext_vector_type(8))) short short8;
typedef __attribute__((ext_vector_type(4))) float f32x4;
typedef __attribute__((ext_vector_type(2))) int i32x2;

__device__ __forceinline__ short bf1(float f) {
    union { __hip_bfloat16 h; short s; } u;
    u.h = __float2bfloat16(f);          // compiler emits v_cvt_pk_bf16_f32 pairs
    return u.s;
}

__device__ __forceinline__ float bf2f(unsigned short u) {
    union { unsigned v; float f; } w; w.v = ((unsigned)u) << 16; return w.f;
}

__device__ __forceinline__ short8 pack8(f32x4 a, f32x4 b) {
    short8 r;
    r[0] = bf1(a[0]); r[1] = bf1(a[1]); r[2] = bf1(a[2]); r[3] = bf1(a[3]);
    r[4] = bf1(b[0]); r[5] = bf1(b[1]); r[6] = bf1(b[2]); r[7] = bf1(b[3]);
    return r;
}

__device__ __forceinline__ f32x4 ntld4(const float* p) {
    return __builtin_nontemporal_load((const f32x4*)p);
}

__device__ __forceinline__ f32x4 ld4(const float* p) {
    return *(const f32x4*)p;
}

#define MFMA16(A, B, C) __builtin_amdgcn_mfma_f32_16x16x32_bf16((A), (B), (C), 0, 0, 0)

// ---------------- k0: Wp = W1@W_fc, Wq = W3@W_fc (bf16 out) ----------------
__global__ __launch_bounds__(256) void k0_wpq(
    const float* __restrict__ W_edge, const float* __restrict__ W_fc,
    unsigned short* __restrict__ wp_bf, unsigned short* __restrict__ wq_bf)
{
    const int i = blockIdx.x * 256 + threadIdx.x;   // 0..8191
    if (i >= 64 * 128) return;
    const int c = i >> 7, k = i & 127;
    float sp = 0.f, sq = 0.f;
    for (int j = 0; j < 64; ++j) {
        const float f = W_fc[j * 128 + k];
        sp += W_edge[c * 192 + j] * f;
        sq += W_edge[c * 192 + 128 + j] * f;
    }
    wp_bf[i] = (unsigned short)bf1(sp);
    wq_bf[i] = (unsigned short)bf1(sq);
}

// ---------------- k12: z/p/q = x @ {W_fc,Wp,Wq}.T via MFMA; deg = 0 ---------
// C/D layout: col = lane&15, row = (lane>>4)*4 + reg (m89-verified).
__global__ __launch_bounds__(256) void k12_node(
    const float* __restrict__ nfeats, const float* __restrict__ W_fc,
    const unsigned short* __restrict__ wp_bf, const unsigned short* __restrict__ wq_bf,
    const float* __restrict__ b_edge,
    unsigned short* __restrict__ z_bf, unsigned short* __restrict__ p_bf,
    unsigned short* __restrict__ q_bf, int* __restrict__ deg, int ntiles)
{
    const int lane = threadIdx.x & 63;
    const int wave = threadIdx.x >> 6;
    const int l15 = lane & 15, g = lane >> 4;
    const int ti = blockIdx.x * 4 + wave;
    if (ti >= ntiles) return;
    const int n0 = ti * 16;

    if (lane < 16) deg[n0 + lane] = 0;   // replaces the memset launch

    // A fragments: 16 nodes x K=128 of nfeats (bf16)
    const float* xp = nfeats + (long)(n0 + l15) * 128 + g * 8;
    short8 Ax[4];
#pragma unroll
    for (int kt = 0; kt < 4; ++kt)
        Ax[kt] = pack8(ntld4(xp + kt * 32), ntld4(xp + kt * 32 + 4));

#pragma unroll
    for (int t = 0; t < 4; ++t) {
        const int col = t * 16 + l15;
        f32x4 az = (f32x4){0.f, 0.f, 0.f, 0.f};
        f32x4 ap = az, aq = az;
#pragma unroll
        for (int kt = 0; kt < 4; ++kt) {
            const float* bz = W_fc + (long)col * 128 + kt * 32 + g * 8;
            az = MFMA16(Ax[kt], pack8(ld4(bz), ld4(bz + 4)), az);
            const short8 bp = *(const short8*)(wp_bf + (long)col * 128 + kt * 32 + g * 8);
            ap = MFMA16(Ax[kt], bp, ap);
            const short8 bq = *(const short8*)(wq_bf + (long)col * 128 + kt * 32 + g * 8);
            aq = MFMA16(Ax[kt], bq, aq);
        }
        const float bias = b_edge[col];
#pragma unroll
        for (int r = 0; r < 4; ++r) {
            const long row = n0 + g * 4 + r;
            z_bf[row * 64 + col] = (unsigned short)bf1(az[r]);
            p_bf[row * 64 + col] = (unsigned short)bf1(ap[r] + bias);
            q_bf[row * 64 + col] = (unsigned short)bf1(aq[r]);
        }
    }
}

// ---------------- K3: per-edge K=192 MFMA + logits + deg/rank ----------------
// R12-exact schedule. ef staged via global_load_lds (per-wave LDS double
// buffer, depth-2). LDS granule (16B) L of a 4KB tile holds GLOBAL granule
//   (L&~15) | ((L&15) ^ ((L>>4)&7))  -- source-side XOR swizzle so the
// stride-256B ds_read_b128 spreads across 8 bank groups.
// C/D layout (m89-verified): col = lane&15, row = (lane>>4)*4 + reg.
#define LOAD_PQ(T, PQ) {                                                    \
    const int sE_ = __shfl(((T) < 4) ? sAll0 : sAll1, ((T)&3) * 16 + l15, 64); \
    const int dE_ = __shfl(((T) < 4) ? dAll0 : dAll1, ((T)&3) * 16 + l15, 64); \
    const unsigned short* pp_ = p_bf + (long)sE_ * 64 + g * 8;              \
    PQ[0] = *(const short8*)pp_;                                            \
    PQ[1] = *(const short8*)(pp_ + 32);                                     \
    const unsigned short* qp_ = q_bf + (long)dE_ * 64 + g * 8;              \
    PQ[2] = *(const short8*)qp_;                                            \
    PQ[3] = *(const short8*)(qp_ + 32);                                     \
}

#define STAGE_EF(T, B) {                                                    \
    const float* gs_ = efeats + (wbase + (T) * 16) * 64;                    \
    _Pragma("unroll")                                                       \
    for (int i_ = 0; i_ < 4; ++i_) {                                        \
        const int L_ = i_ * 64 + lane;                                      \
        const int G_ = (L_ & ~15) | ((L_ & 15) ^ ((L_ >> 4) & 7));          \
        __builtin_amdgcn_global_load_lds(                                   \
            (const __attribute__((address_space(1))) unsigned int*)(gs_ + G_ * 4), \
            (__attribute__((address_space(3))) unsigned int*)(&efb[wave][B][i_ * 256]), \
            16, 0, 0);                                                      \
    }                                                                       \
}

#define EF_READ(B, E0, E1, E2, E3) {                                        \
    const float* eb2_ = &efb[wave][B][0];                                   \
    const int ro_ = l15 * 64, sx_ = l15 & 7;                                \
    E0 = *(const f32x4*)(eb2_ + ro_ + (((2 * g    ) ^ sx_) << 2));          \
    E1 = *(const f32x4*)(eb2_ + ro_ + (((2 * g + 1) ^ sx_) << 2));          \
    E2 = *(const f32x4*)(eb2_ + ro_ + (((2 * g + 8) ^ sx_) << 2));          \
    E3 = *(const f32x4*)(eb2_ + ro_ + (((2 * g + 9) ^ sx_) << 2));          \
}

#define VMW asm volatile("s_waitcnt vmcnt(40)" ::: "memory");

#define DO_TILE(T, PQ, BUF, DOWAIT, PREFETCH) {                             \
    const long eb_ = wbase + (T) * 16;                                      \
    DOWAIT                                                                  \
    f32x4 e0_, e1_, e2_, e3_;                                               \
    EF_READ(BUF, e0_, e1_, e2_, e3_);                                       \
    asm volatile("s_waitcnt lgkmcnt(0)" ::: "memory");                      \
    PREFETCH                                                                \
    f32x4 acc_[4];                                                          \
    _Pragma("unroll")                                                       \
    for (int t = 0; t < 4; ++t) acc_[t] = (f32x4){0.f, 0.f, 0.f, 0.f};      \
    acc_[0] = MFMA16(PQ[0], IdA, acc_[0]);                                  \
    acc_[1] = MFMA16(PQ[0], IdB, acc_[1]);                                  \
    acc_[2] = MFMA16(PQ[1], IdA, acc_[2]);                                  \
    acc_[3] = MFMA16(PQ[1], IdB, acc_[3]);                                  \
    acc_[0] = MFMA16(PQ[2], IdA, acc_[0]);                                  \
    acc_[1] = MFMA16(PQ[2], IdB, acc_[1]);                                  \
    acc_[2] = MFMA16(PQ[3], IdA, acc_[2]);                                  \
    acc_[3] = MFMA16(PQ[3], IdB, acc_[3]);                                  \
    short8 Aef0_ = pack8(e0_, e1_), Aef1_ = pack8(e2_, e3_);                \
    _Pragma("unroll")                                                       \
    for (int t = 0; t < 4; ++t) {                                           \
        acc_[t] = MFMA16(Aef0_, W2f[t * 64 + lane], acc_[t]);               \
        acc_[t] = MFMA16(Aef1_, W2f[(4 + t) * 64 + lane], acc_[t]);         \
    }                                                                       \
    float myex_ = 0.f;                                                      \
    _Pragma("unroll")                                                       \
    for (int r = 0; r < 4; ++r) {                                           \
        float s_ = 0.f;                                                     \
        _Pragma("unroll")                                                   \
        for (int t = 0; t < 4; ++t) {                                       \
            float v_ = acc_[t][r];                                          \
            v_ = (v_ >= 0.f) ? v_ : 0.01f * v_;                             \
            __builtin_nontemporal_store(v_,                                 \
                feat_out + (eb_ + g * 4 + r) * 64 + t * 16 + l15);          \
            s_ += v_ * wc[t];                                               \
        }                                                                   \
        s_ += __shfl_xor(s_, 1, 16);                                        \
        s_ += __shfl_xor(s_, 2, 16);                                        \
        s_ += __shfl_xor(s_, 4, 16);                                        \
        s_ += __shfl_xor(s_, 8, 16);                                        \
        s_ = (s_ >= 0.f) ? s_ : 0.01f * s_;                                 \
        s_ = (s_ >= 0.f) ? s_ : 0.01f * s_;                                 \
        const float ex_ = __expf(s_);                                       \
        if (l15 == r) myex_ = ex_;                                          \
    }                                                                       \
    const int dmine_ = __shfl(((T) < 4) ? dAll0 : dAll1,                    \
                              ((T)&3) * 16 + g * 4 + (l15 & 3), 64);        \
    if (l15 < 4) {                                                          \
        exbuf[eb_ + g * 4 + l15] = myex_;                                   \
        rank[eb_ + g * 4 + l15] = atomicAdd(&deg[dmine_], 1);               \
    }                                                                       \
}

__global__ __launch_bounds__(256, 4) void k3_edges(
    const float* __restrict__ efeats, const int* __restrict__ src,
    const int* __restrict__ dst, const float* __restrict__ W_edge,
    const float* __restrict__ w_coef, const unsigned short* __restrict__ p_bf,
    const unsigned short* __restrict__ q_bf, float* __restrict__ feat_out,
    float* __restrict__ exbuf, int* __restrict__ deg, int* __restrict__ rank)
{
    __shared__ short8 W2f[512];        // pre-packed W2 B-frags, 8KB
    __shared__ float efb[4][2][1024];  // [wave][buf][4KB ef tile], 32KB

    const int tid = threadIdx.x;
    const int lane = tid & 63;
    const int wave = tid >> 6;
    const int l15 = lane & 15, g = lane >> 4;
    const long wbase = ((long)blockIdx.x * 4 + wave) * 128;

    // stage tiles 0,1 (drained by the __syncthreads below)
    STAGE_EF(0, 0);
    const int sAll0 = src[wbase + lane];
    const int dAll0 = dst[wbase + lane];
    const int sAll1 = src[wbase + 64 + lane];
    const int dAll1 = dst[wbase + 64 + lane];
    STAGE_EF(1, 1);

    // fill W2 fragment LDS: frag fi -> (s = fi>>6, l = fi&63)
#pragma unroll
    for (int jj = 0; jj < 2; ++jj) {
        const int fi = tid + jj * 256;
        const int s = fi >> 6, l = fi & 63;
        const int col = (s & 3) * 16 + (l & 15);
        const int gg = l >> 4, kt = s >> 2;
        const float* wp = W_edge + col * 192 + 64 + kt * 32 + gg * 8;
        W2f[fi] = pack8(ld4(wp), ld4(wp + 4));
    }

    float wc[4];
#pragma unroll
    for (int t = 0; t < 4; ++t) wc[t] = w_coef[t * 16 + l15];

    // identity B-fragments: one-hot at kc == col (mod 32 block)
    const short one = (short)0x3F80;   // bf16 1.0
    short8 IdA, IdB;
#pragma unroll
    for (int jj = 0; jj < 8; ++jj) {
        IdA[jj] = (l15 == g * 8 + jj) ? one : (short)0;        // cols 0..15 / 32..47
        IdB[jj] = (16 + l15 == g * 8 + jj) ? one : (short)0;   // cols 16..31 / 48..63
    }
    __syncthreads();   // W2f visible; vmcnt(0) drain => tiles 0,1 staged

    short8 pqA[4], pqB[4];
    LOAD_PQ(0, pqA);
    DO_TILE(0, pqA, 0, , { STAGE_EF(2, 0); LOAD_PQ(1, pqB); });
    DO_TILE(1, pqB, 1, , { STAGE_EF(3, 1); LOAD_PQ(2, pqA); });
    DO_TILE(2, pqA, 0, VMW, { STAGE_EF(4, 0); LOAD_PQ(3, pqB); });
    DO_TILE(3, pqB, 1, VMW, { STAGE_EF(5, 1); LOAD_PQ(4, pqA); });
    DO_TILE(4, pqA, 0, VMW, { STAGE_EF(6, 0); LOAD_PQ(5, pqB); });
    DO_TILE(5, pqB, 1, VMW, { STAGE_EF(7, 1); LOAD_PQ(6, pqA); });
    DO_TILE(6, pqA, 0, VMW, { LOAD_PQ(7, pqB); });
    DO_TILE(7, pqB, 1, VMW, );
}

// ---------------- scan1: per-block (1024 elems) totals ----------------
__global__ __launch_bounds__(256) void k_scan1(
    const int* __restrict__ deg, int* __restrict__ bsum, int N)
{
    __shared__ int ws4[4];
    const int tid = threadIdx.x, lane = tid & 63, wave = tid >> 6;
    const int i0 = blockIdx.x * 1024 + tid * 4;
    int s = 0;
#pragma unroll
    for (int jj = 0; jj < 4; ++jj) {
        const int i = i0 + jj;
        if (i < N) s += deg[i];
    }
#pragma unroll
    for (int d = 1; d < 64; d <<= 1) s += __shfl_xor(s, d, 64);
    if (lane == 0) ws4[wave] = s;
    __syncthreads();
    if (tid == 0) bsum[blockIdx.x] = ws4[0] + ws4[1] + ws4[2] + ws4[3];
}

// ---------------- scan2: scan of block totals (<=64 blocks) ----------------
__global__ __launch_bounds__(64) void k_scan2(
    const int* __restrict__ bsum, int* __restrict__ bpre,
    int* __restrict__ off, int nb, int N)
{
    const int t = threadIdx.x;
    const int v = (t < nb) ? bsum[t] : 0;
    int x = v;
#pragma unroll
    for (int d = 1; d < 64; d <<= 1) {
        int y = __shfl_up(x, d, 64);
        if (t >= d) x += y;
    }
    if (t < nb) bpre[t] = x - v;
    if (t == 63) off[N] = x;   // grand total == E
}

// ---------------- scan3: write off[i] ----------------
__global__ __launch_bounds__(256) void k_scan3(
    const int* __restrict__ deg, const int* __restrict__ bpre,
    int* __restrict__ off, int N)
{
    __shared__ int ws4[4];
    const int tid = threadIdx.x, lane = tid & 63, wave = tid >> 6;
    const int i0 = blockIdx.x * 1024 + tid * 4;
    int v[4];
#pragma unroll
    for (int jj = 0; jj < 4; ++jj) {
        const int i = i0 + jj;
        v[jj] = (i < N) ? deg[i] : 0;
    }
    const int s = v[0] + v[1] + v[2] + v[3];
    int x = s;
#pragma unroll
    for (int d = 1; d < 64; d <<= 1) {
        int y = __shfl_up(x, d, 64);
        if (lane >= d) x += y;
    }
    if (lane == 63) ws4[wave] = x;
    __syncthreads();
    int wpre = 0;
#pragma unroll
    for (int w = 0; w < 4; ++w) if (w < wave) wpre += ws4[w];
    int run = bpre[blockIdx.x] + wpre + (x - s);
#pragma unroll
    for (int jj = 0; jj < 4; ++jj) {
        const int i = i0 + jj;
        if (i < N) off[i] = run;
        run += v[jj];
    }
}

// ---------------- scatter (atomic-free): pairs[off[d]+rank[e]] = {src, ex} ----
__global__ __launch_bounds__(256) void k_scatter(
    const int* __restrict__ src, const int* __restrict__ dst,
    const float* __restrict__ exbuf, const int* __restrict__ off,
    const int* __restrict__ rank, i32x2* __restrict__ pairs, long E)
{
    const long e = (long)blockIdx.x * 256 + threadIdx.x;
    if (e >= E) return;
    const int d = dst[e];
    const int pos = off[d] + rank[e];
    i32x2 pr;
    pr[0] = src[e];
    pr[1] = __float_as_int(exbuf[e]);
    pairs[pos] = pr;
}

// ---------------- K5: h[n] = sum(ex*z[src]) / sum(ex) ----------------
// one wave per node; lane = channel; z gathered as bf16 (128B rows).
__global__ __launch_bounds__(256) void k5_aggregate(
    const int* __restrict__ off, const i32x2* __restrict__ pairs,
    const unsigned short* __restrict__ z_bf, float* __restrict__ h, int N)
{
    const int wave = threadIdx.x >> 6, lane = threadIdx.x & 63;
    const int n = blockIdx.x * 4 + wave;
    if (n >= N) return;
    const int beg = off[n], end = off[n + 1];
    float den = 0.f;
    float a0 = 0.f, a1 = 0.f, a2 = 0.f, a3 = 0.f;
    for (int base = beg; base < end; base += 64) {
        const int rem = end - base;
        i32x2 pr = (i32x2){0, 0};
        if (lane < rem) pr = __builtin_nontemporal_load(&pairs[base + lane]);
        const float ex = __int_as_float(pr[1]);
        float t = ex;
#pragma unroll
        for (int d = 1; d < 64; d <<= 1) t += __shfl_xor(t, d, 64);
        den += t;
        const int cnt = rem < 64 ? rem : 64;
        const int cnt4 = (cnt + 3) & ~3;
        for (int j = 0; j < cnt4; j += 4) {
            const int s0 = __shfl(pr[0], j, 64);
            const int s1 = __shfl(pr[0], j + 1, 64);
            const int s2 = __shfl(pr[0], j + 2, 64);
            const int s3 = __shfl(pr[0], j + 3, 64);
            const float e0 = __shfl(ex, j, 64);
            const float e1 = __shfl(ex, j + 1, 64);
            const float e2 = __shfl(ex, j + 2, 64);
            const float e3 = __shfl(ex, j + 3, 64);
            a0 = fmaf(e0, bf2f(z_bf[(long)s0 * 64 + lane]), a0);
            a1 = fmaf(e1, bf2f(z_bf[(long)s1 * 64 + lane]), a1);
            a2 = fmaf(e2, bf2f(z_bf[(long)s2 * 64 + lane]), a2);
            a3 = fmaf(e3, bf2f(z_bf[(long)s3 * 64 + lane]), a3);
        }
    }
    const float acc = (a0 + a1) + (a2 + a3);
    __builtin_nontemporal_store((end > beg) ? acc / den : 0.f,
                                h + (long)n * 64 + lane);
}

extern "C" void kernel_launch(void* const* d_in, const int* in_sizes, int n_in,
                              void* d_out, int out_size, void* d_ws, size_t ws_size,
                              hipStream_t stream) {
    const float* nfeats = (const float*)d_in[0];
    const float* efeats = (const float*)d_in[1];
    const int*   src    = (const int*)d_in[2];
    const int*   dst    = (const int*)d_in[3];
    const float* W_fc   = (const float*)d_in[4];
    const float* W_edge = (const float*)d_in[5];
    const float* b_edge = (const float*)d_in[6];
    const float* w_coef = (const float*)d_in[7];

    const int  N = in_sizes[0] / 128;   // 50000
    const long E = in_sizes[2];         // 1600000
    const int  nb = (N + 1023) / 1024;  // 49
    const int  ntiles = N / 16;         // 3125

    float* h    = (float*)d_out;                 // [N,64]
    float* feat = (float*)d_out + (long)N * 64;  // [E,64]

    unsigned short* z_bf   = (unsigned short*)d_ws;        // N*64 bf16
    unsigned short* p_bf   = z_bf + (long)N * 64;          // N*64 bf16
    unsigned short* q_bf   = p_bf + (long)N * 64;          // N*64 bf16
    unsigned short* wp_bf  = q_bf + (long)N * 64;          // 64*128
    unsigned short* wq_bf  = wp_bf + 64 * 128;             // 64*128
    float*          exbuf  = (float*)(wq_bf + 64 * 128);   // E
    int*            deg    = (int*)(exbuf + E);            // N
    int*            rank   = deg + N;                      // E
    int*            off    = rank + E;                     // N+2 (8B-align pairs)
    i32x2*          pairs  = (i32x2*)(off + N + 2);        // E
    int*            bsum   = (int*)(pairs + E);            // 64
    int*            bpre   = bsum + 64;                    // 64

    k0_wpq<<<32, 256, 0, stream>>>(W_edge, W_fc, wp_bf, wq_bf);
    k12_node<<<(ntiles + 3) / 4, 256, 0, stream>>>(nfeats, W_fc, wp_bf, wq_bf,
                                                   b_edge, z_bf, p_bf, q_bf,
                                                   deg, ntiles);
    k3_edges<<<(int)(E / 512), 256, 0, stream>>>(efeats, src, dst, W_edge, w_coef,
                                                 p_bf, q_bf, feat, exbuf, deg, rank);
    k_scan1<<<nb, 256, 0, stream>>>(deg, bsum, N);
    k_scan2<<<1, 64, 0, stream>>>(bsum, bpre, off, nb, N);
    k_scan3<<<nb, 256, 0, stream>>>(deg, bpre, off, N);
    k_scatter<<<(int)((E + 255) / 256), 256, 0, stream>>>(src, dst, exbuf, off,
                                                          rank, pairs, E);
    k5_aggregate<<<(N + 3) / 4, 256, 0, stream>>>(off, pairs, z_bf, h, N);
}

// Round 18
// 344.056 us; speedup vs baseline: 1.3686x; 1.0137x over previous
//
#include <hip/hip_runtime.h>
#include <hip/hip_bf16.h>

// GAT layer: N=50000 nodes, E=1.6M edges, DIN_N=128, DIN_E=64, DOUT_N=DOUT_E=64.
//   Wp = W1@W_fc, Wq = W3@W_fc                           (k0, 64x128 each, bf16)
//   z = x@W_fc.T; p = x@Wp.T + b; q = x@Wq.T             (k12, one MFMA GEMM, bf16 out;
//                                                         also zeroes deg)
//   feat[e] = lrelu([ef | p[src] | q[dst]] @ [W2; I; I])  (K3, K=192 MFMA,
//                         identity-B frags do the A->C transpose of p/q)
//   a = lrelu(lrelu(feat . wc)); ex = exp(a);
//   rank[e] = deg[dst]++  (atomic return value)           (K3)
//   off = exscan(deg)  (scan1/2/3)
//   pairs[off[dst]+rank[e]] = {src, ex}                   (scatter, NO atomics)
//   h[n] = sum(ex * z_bf[src]) / sum(ex)                  (K5, wave/node)
// Segment-max skipped: a is O(+-4) so exp cannot overflow; alpha identical.
// R17->R18: R16's single-ef-buffer k3 (24KB LDS -> 6 blocks/CU) was correct
// but spilled ONLY because (256,6) capped regs at ~80. launch_bounds' 2nd arg
// caps registers, not occupancy: with (256,4) (cap 128) the kernel should
// compile ~56-72 VGPR and occupancy becomes LDS-limited at 6 blocks/CU
// (24 waves, was 16). vmcnt(16) per tile (19 newer vmem ops after stage).

typedef __attribute__((ext_vector_type(8))) short short8;
typedef __attribute__((ext_vector_type(4))) float f32x4;
typedef __attribute__((ext_vector_type(2))) int i32x2;

__device__ __forceinline__ short bf1(float f) {
    union { __hip_bfloat16 h; short s; } u;
    u.h = __float2bfloat16(f);          // compiler emits v_cvt_pk_bf16_f32 pairs
    return u.s;
}

__device__ __forceinline__ float bf2f(unsigned short u) {
    union { unsigned v; float f; } w; w.v = ((unsigned)u) << 16; return w.f;
}

__device__ __forceinline__ short8 pack8(f32x4 a, f32x4 b) {
    short8 r;
    r[0] = bf1(a[0]); r[1] = bf1(a[1]); r[2] = bf1(a[2]); r[3] = bf1(a[3]);
    r[4] = bf1(b[0]); r[5] = bf1(b[1]); r[6] = bf1(b[2]); r[7] = bf1(b[3]);
    return r;
}

__device__ __forceinline__ f32x4 ntld4(const float* p) {
    return __builtin_nontemporal_load((const f32x4*)p);
}

__device__ __forceinline__ f32x4 ld4(const float* p) {
    return *(const f32x4*)p;
}

#define MFMA16(A, B, C) __builtin_amdgcn_mfma_f32_16x16x32_bf16((A), (B), (C), 0, 0, 0)

// ---------------- k0: Wp = W1@W_fc, Wq = W3@W_fc (bf16 out) ----------------
__global__ __launch_bounds__(256) void k0_wpq(
    const float* __restrict__ W_edge, const float* __restrict__ W_fc,
    unsigned short* __restrict__ wp_bf, unsigned short* __restrict__ wq_bf)
{
    const int i = blockIdx.x * 256 + threadIdx.x;   // 0..8191
    if (i >= 64 * 128) return;
    const int c = i >> 7, k = i & 127;
    float sp = 0.f, sq = 0.f;
    for (int j = 0; j < 64; ++j) {
        const float f = W_fc[j * 128 + k];
        sp += W_edge[c * 192 + j] * f;
        sq += W_edge[c * 192 + 128 + j] * f;
    }
    wp_bf[i] = (unsigned short)bf1(sp);
    wq_bf[i] = (unsigned short)bf1(sq);
}

// ---------------- k12: z/p/q = x @ {W_fc,Wp,Wq}.T via MFMA; deg = 0 ---------
// C/D layout: col = lane&15, row = (lane>>4)*4 + reg (m89-verified).
__global__ __launch_bounds__(256) void k12_node(
    const float* __restrict__ nfeats, const float* __restrict__ W_fc,
    const unsigned short* __restrict__ wp_bf, const unsigned short* __restrict__ wq_bf,
    const float* __restrict__ b_edge,
    unsigned short* __restrict__ z_bf, unsigned short* __restrict__ p_bf,
    unsigned short* __restrict__ q_bf, int* __restrict__ deg, int ntiles)
{
    const int lane = threadIdx.x & 63;
    const int wave = threadIdx.x >> 6;
    const int l15 = lane & 15, g = lane >> 4;
    const int ti = blockIdx.x * 4 + wave;
    if (ti >= ntiles) return;
    const int n0 = ti * 16;

    if (lane < 16) deg[n0 + lane] = 0;   // replaces the memset launch

    // A fragments: 16 nodes x K=128 of nfeats (bf16)
    const float* xp = nfeats + (long)(n0 + l15) * 128 + g * 8;
    short8 Ax[4];
#pragma unroll
    for (int kt = 0; kt < 4; ++kt)
        Ax[kt] = pack8(ntld4(xp + kt * 32), ntld4(xp + kt * 32 + 4));

#pragma unroll
    for (int t = 0; t < 4; ++t) {
        const int col = t * 16 + l15;
        f32x4 az = (f32x4){0.f, 0.f, 0.f, 0.f};
        f32x4 ap = az, aq = az;
#pragma unroll
        for (int kt = 0; kt < 4; ++kt) {
            const float* bz = W_fc + (long)col * 128 + kt * 32 + g * 8;
            az = MFMA16(Ax[kt], pack8(ld4(bz), ld4(bz + 4)), az);
            const short8 bp = *(const short8*)(wp_bf + (long)col * 128 + kt * 32 + g * 8);
            ap = MFMA16(Ax[kt], bp, ap);
            const short8 bq = *(const short8*)(wq_bf + (long)col * 128 + kt * 32 + g * 8);
            aq = MFMA16(Ax[kt], bq, aq);
        }
        const float bias = b_edge[col];
#pragma unroll
        for (int r = 0; r < 4; ++r) {
            const long row = n0 + g * 4 + r;
            z_bf[row * 64 + col] = (unsigned short)bf1(az[r]);
            p_bf[row * 64 + col] = (unsigned short)bf1(ap[r] + bias);
            q_bf[row * 64 + col] = (unsigned short)bf1(aq[r]);
        }
    }
}

// ---------------- K3: per-edge K=192 MFMA + logits + deg/rank ----------------
// ef staged via global_load_lds into a SINGLE 4KB buffer per wave (24KB/block
// incl. W2f -> 6 blocks/CU at VGPR<=85). LDS granule (16B) L of a 4KB tile
// holds GLOBAL granule (L&~15) | ((L&15) ^ ((L>>4)&7)) -- source-side XOR
// swizzle so the stride-256B ds_read_b128 spreads across 8 bank groups.
// Per-tile: vmcnt(16) waits the stage issued last tile (19 newer vmem ops:
// 16 feat stores + exbuf + rank + atomicAdd; margin 3). lgkmcnt(0) orders
// this tile's ds_reads before the same-buffer restage.
// C/D layout (m89-verified): col = lane&15, row = (lane>>4)*4 + reg.
#define LOAD_PQ(T, PQ) {                                                    \
    const int sE_ = __shfl(((T) < 4) ? sAll0 : sAll1, ((T)&3) * 16 + l15, 64); \
    const int dE_ = __shfl(((T) < 4) ? dAll0 : dAll1, ((T)&3) * 16 + l15, 64); \
    const unsigned short* pp_ = p_bf + (long)sE_ * 64 + g * 8;              \
    PQ[0] = *(const short8*)pp_;                                            \
    PQ[1] = *(const short8*)(pp_ + 32);                                     \
    const unsigned short* qp_ = q_bf + (long)dE_ * 64 + g * 8;              \
    PQ[2] = *(const short8*)qp_;                                            \
    PQ[3] = *(const short8*)(qp_ + 32);                                     \
}

#define STAGE_EF(T) {                                                       \
    const float* gs_ = efeats + (wbase + (T) * 16) * 64;                    \
    _Pragma("unroll")                                                       \
    for (int i_ = 0; i_ < 4; ++i_) {                                        \
        const int L_ = i_ * 64 + lane;                                      \
        const int G_ = (L_ & ~15) | ((L_ & 15) ^ ((L_ >> 4) & 7));          \
        __builtin_amdgcn_global_load_lds(                                   \
            (const __attribute__((address_space(1))) unsigned int*)(gs_ + G_ * 4), \
            (__attribute__((address_space(3))) unsigned int*)(&efb[wave][i_ * 256]), \
            16, 0, 0);                                                      \
    }                                                                       \
}

#define EF_READ(E0, E1, E2, E3) {                                           \
    const float* eb2_ = &efb[wave][0];                                      \
    const int ro_ = l15 * 64, sx_ = l15 & 7;                                \
    E0 = *(const f32x4*)(eb2_ + ro_ + (((2 * g    ) ^ sx_) << 2));          \
    E1 = *(const f32x4*)(eb2_ + ro_ + (((2 * g + 1) ^ sx_) << 2));          \
    E2 = *(const f32x4*)(eb2_ + ro_ + (((2 * g + 8) ^ sx_) << 2));          \
    E3 = *(const f32x4*)(eb2_ + ro_ + (((2 * g + 9) ^ sx_) << 2));          \
}

#define VMW asm volatile("s_waitcnt vmcnt(16)" ::: "memory");

#define DO_TILE(T, PQ, DOWAIT, DOPQ, DOSTAGE) {                             \
    const long eb_ = wbase + (T) * 16;                                      \
    DOWAIT                                                                  \
    f32x4 e0_, e1_, e2_, e3_;                                               \
    EF_READ(e0_, e1_, e2_, e3_);                                            \
    DOPQ                                                                    \
    asm volatile("s_waitcnt lgkmcnt(0)" ::: "memory");                      \
    DOSTAGE                                                                 \
    f32x4 acc_[4];                                                          \
    _Pragma("unroll")                                                       \
    for (int t = 0; t < 4; ++t) acc_[t] = (f32x4){0.f, 0.f, 0.f, 0.f};      \
    acc_[0] = MFMA16(PQ[0], IdA, acc_[0]);                                  \
    acc_[1] = MFMA16(PQ[0], IdB, acc_[1]);                                  \
    acc_[2] = MFMA16(PQ[1], IdA, acc_[2]);                                  \
    acc_[3] = MFMA16(PQ[1], IdB, acc_[3]);                                  \
    acc_[0] = MFMA16(PQ[2], IdA, acc_[0]);                                  \
    acc_[1] = MFMA16(PQ[2], IdB, acc_[1]);                                  \
    acc_[2] = MFMA16(PQ[3], IdA, acc_[2]);                                  \
    acc_[3] = MFMA16(PQ[3], IdB, acc_[3]);                                  \
    short8 Aef0_ = pack8(e0_, e1_), Aef1_ = pack8(e2_, e3_);                \
    _Pragma("unroll")                                                       \
    for (int t = 0; t < 4; ++t) {                                           \
        acc_[t] = MFMA16(Aef0_, W2f[t * 64 + lane], acc_[t]);               \
        acc_[t] = MFMA16(Aef1_, W2f[(4 + t) * 64 + lane], acc_[t]);         \
    }                                                                       \
    float myex_ = 0.f;                                                      \
    _Pragma("unroll")                                                       \
    for (int r = 0; r < 4; ++r) {                                           \
        float s_ = 0.f;                                                     \
        _Pragma("unroll")                                                   \
        for (int t = 0; t < 4; ++t) {                                       \
            float v_ = acc_[t][r];                                          \
            v_ = (v_ >= 0.f) ? v_ : 0.01f * v_;                             \
            __builtin_nontemporal_store(v_,                                 \
                feat_out + (eb_ + g * 4 + r) * 64 + t * 16 + l15);          \
            s_ += v_ * wc[t];                                               \
        }                                                                   \
        s_ += __shfl_xor(s_, 1, 16);                                        \
        s_ += __shfl_xor(s_, 2, 16);                                        \
        s_ += __shfl_xor(s_, 4, 16);                                        \
        s_ += __shfl_xor(s_, 8, 16);                                        \
        s_ = (s_ >= 0.f) ? s_ : 0.01f * s_;                                 \
        s_ = (s_ >= 0.f) ? s_ : 0.01f * s_;                                 \
        const float ex_ = __expf(s_);                                       \
        if (l15 == r) myex_ = ex_;                                          \
    }                                                                       \
    const int dmine_ = __shfl(((T) < 4) ? dAll0 : dAll1,                    \
                              ((T)&3) * 16 + g * 4 + (l15 & 3), 64);        \
    if (l15 < 4) {                                                          \
        exbuf[eb_ + g * 4 + l15] = myex_;                                   \
        rank[eb_ + g * 4 + l15] = atomicAdd(&deg[dmine_], 1);               \
    }                                                                       \
}

__global__ __launch_bounds__(256, 4) void k3_edges(
    const float* __restrict__ efeats, const int* __restrict__ src,
    const int* __restrict__ dst, const float* __restrict__ W_edge,
    const float* __restrict__ w_coef, const unsigned short* __restrict__ p_bf,
    const unsigned short* __restrict__ q_bf, float* __restrict__ feat_out,
    float* __restrict__ exbuf, int* __restrict__ deg, int* __restrict__ rank)
{
    __shared__ short8 W2f[512];     // pre-packed W2 B-frags, 8KB
    __shared__ float efb[4][1024];  // [wave][4KB ef tile], 16KB -> 24KB total

    const int tid = threadIdx.x;
    const int lane = tid & 63;
    const int wave = tid >> 6;
    const int l15 = lane & 15, g = lane >> 4;
    const long wbase = ((long)blockIdx.x * 4 + wave) * 128;

    // stage tile 0 (drained by the __syncthreads below)
    STAGE_EF(0);
    const int sAll0 = src[wbase + lane];
    const int dAll0 = dst[wbase + lane];
    const int sAll1 = src[wbase + 64 + lane];
    const int dAll1 = dst[wbase + 64 + lane];

    // fill W2 fragment LDS: frag fi -> (s = fi>>6, l = fi&63)
#pragma unroll
    for (int jj = 0; jj < 2; ++jj) {
        const int fi = tid + jj * 256;
        const int s = fi >> 6, l = fi & 63;
        const int col = (s & 3) * 16 + (l & 15);
        const int gg = l >> 4, kt = s >> 2;
        const float* wp = W_edge + col * 192 + 64 + kt * 32 + gg * 8;
        W2f[fi] = pack8(ld4(wp), ld4(wp + 4));
    }

    float wc[4];
#pragma unroll
    for (int t = 0; t < 4; ++t) wc[t] = w_coef[t * 16 + l15];

    // identity B-fragments: one-hot at kc == col (mod 32 block)
    const short one = (short)0x3F80;   // bf16 1.0
    short8 IdA, IdB;
#pragma unroll
    for (int jj = 0; jj < 8; ++jj) {
        IdA[jj] = (l15 == g * 8 + jj) ? one : (short)0;        // cols 0..15 / 32..47
        IdB[jj] = (16 + l15 == g * 8 + jj) ? one : (short)0;   // cols 16..31 / 48..63
    }

    short8 pqA[4], pqB[4];
    LOAD_PQ(0, pqA);
    __syncthreads();   // W2f visible; vmcnt(0)+lgkmcnt(0) drain: tile 0 staged

    DO_TILE(0, pqA, ,    { LOAD_PQ(1, pqB); }, { STAGE_EF(1); });
    DO_TILE(1, pqB, VMW, { LOAD_PQ(2, pqA); }, { STAGE_EF(2); });
    DO_TILE(2, pqA, VMW, { LOAD_PQ(3, pqB); }, { STAGE_EF(3); });
    DO_TILE(3, pqB, VMW, { LOAD_PQ(4, pqA); }, { STAGE_EF(4); });
    DO_TILE(4, pqA, VMW, { LOAD_PQ(5, pqB); }, { STAGE_EF(5); });
    DO_TILE(5, pqB, VMW, { LOAD_PQ(6, pqA); }, { STAGE_EF(6); });
    DO_TILE(6, pqA, VMW, { LOAD_PQ(7, pqB); }, { STAGE_EF(7); });
    DO_TILE(7, pqB, VMW, , );
}

// ---------------- scan1: per-block (1024 elems) totals ----------------
__global__ __launch_bounds__(256) void k_scan1(
    const int* __restrict__ deg, int* __restrict__ bsum, int N)
{
    __shared__ int ws4[4];
    const int tid = threadIdx.x, lane = tid & 63, wave = tid >> 6;
    const int i0 = blockIdx.x * 1024 + tid * 4;
    int s = 0;
#pragma unroll
    for (int jj = 0; jj < 4; ++jj) {
        const int i = i0 + jj;
        if (i < N) s += deg[i];
    }
#pragma unroll
    for (int d = 1; d < 64; d <<= 1) s += __shfl_xor(s, d, 64);
    if (lane == 0) ws4[wave] = s;
    __syncthreads();
    if (tid == 0) bsum[blockIdx.x] = ws4[0] + ws4[1] + ws4[2] + ws4[3];
}

// ---------------- scan2: scan of block totals (<=64 blocks) ----------------
__global__ __launch_bounds__(64) void k_scan2(
    const int* __restrict__ bsum, int* __restrict__ bpre,
    int* __restrict__ off, int nb, int N)
{
    const int t = threadIdx.x;
    const int v = (t < nb) ? bsum[t] : 0;
    int x = v;
#pragma unroll
    for (int d = 1; d < 64; d <<= 1) {
        int y = __shfl_up(x, d, 64);
        if (t >= d) x += y;
    }
    if (t < nb) bpre[t] = x - v;
    if (t == 63) off[N] = x;   // grand total == E
}

// ---------------- scan3: write off[i] ----------------
__global__ __launch_bounds__(256) void k_scan3(
    const int* __restrict__ deg, const int* __restrict__ bpre,
    int* __restrict__ off, int N)
{
    __shared__ int ws4[4];
    const int tid = threadIdx.x, lane = tid & 63, wave = tid >> 6;
    const int i0 = blockIdx.x * 1024 + tid * 4;
    int v[4];
#pragma unroll
    for (int jj = 0; jj < 4; ++jj) {
        const int i = i0 + jj;
        v[jj] = (i < N) ? deg[i] : 0;
    }
    const int s = v[0] + v[1] + v[2] + v[3];
    int x = s;
#pragma unroll
    for (int d = 1; d < 64; d <<= 1) {
        int y = __shfl_up(x, d, 64);
        if (lane >= d) x += y;
    }
    if (lane == 63) ws4[wave] = x;
    __syncthreads();
    int wpre = 0;
#pragma unroll
    for (int w = 0; w < 4; ++w) if (w < wave) wpre += ws4[w];
    int run = bpre[blockIdx.x] + wpre + (x - s);
#pragma unroll
    for (int jj = 0; jj < 4; ++jj) {
        const int i = i0 + jj;
        if (i < N) off[i] = run;
        run += v[jj];
    }
}

// ---------------- scatter (atomic-free): pairs[off[d]+rank[e]] = {src, ex} ----
__global__ __launch_bounds__(256) void k_scatter(
    const int* __restrict__ src, const int* __restrict__ dst,
    const float* __restrict__ exbuf, const int* __restrict__ off,
    const int* __restrict__ rank, i32x2* __restrict__ pairs, long E)
{
    const long e = (long)blockIdx.x * 256 + threadIdx.x;
    if (e >= E) return;
    const int d = dst[e];
    const int pos = off[d] + rank[e];
    i32x2 pr;
    pr[0] = src[e];
    pr[1] = __float_as_int(exbuf[e]);
    pairs[pos] = pr;
}

// ---------------- K5: h[n] = sum(ex*z[src]) / sum(ex) ----------------
// one wave per node; lane = channel; z gathered as bf16 (128B rows).
__global__ __launch_bounds__(256) void k5_aggregate(
    const int* __restrict__ off, const i32x2* __restrict__ pairs,
    const unsigned short* __restrict__ z_bf, float* __restrict__ h, int N)
{
    const int wave = threadIdx.x >> 6, lane = threadIdx.x & 63;
    const int n = blockIdx.x * 4 + wave;
    if (n >= N) return;
    const int beg = off[n], end = off[n + 1];
    float den = 0.f;
    float a0 = 0.f, a1 = 0.f, a2 = 0.f, a3 = 0.f;
    for (int base = beg; base < end; base += 64) {
        const int rem = end - base;
        i32x2 pr = (i32x2){0, 0};
        if (lane < rem) pr = __builtin_nontemporal_load(&pairs[base + lane]);
        const float ex = __int_as_float(pr[1]);
        float t = ex;
#pragma unroll
        for (int d = 1; d < 64; d <<= 1) t += __shfl_xor(t, d, 64);
        den += t;
        const int cnt = rem < 64 ? rem : 64;
        const int cnt4 = (cnt + 3) & ~3;
        for (int j = 0; j < cnt4; j += 4) {
            const int s0 = __shfl(pr[0], j, 64);
            const int s1 = __shfl(pr[0], j + 1, 64);
            const int s2 = __shfl(pr[0], j + 2, 64);
            const int s3 = __shfl(pr[0], j + 3, 64);
            const float e0 = __shfl(ex, j, 64);
            const float e1 = __shfl(ex, j + 1, 64);
            const float e2 = __shfl(ex, j + 2, 64);
            const float e3 = __shfl(ex, j + 3, 64);
            a0 = fmaf(e0, bf2f(z_bf[(long)s0 * 64 + lane]), a0);
            a1 = fmaf(e1, bf2f(z_bf[(long)s1 * 64 + lane]), a1);
            a2 = fmaf(e2, bf2f(z_bf[(long)s2 * 64 + lane]), a2);
            a3 = fmaf(e3, bf2f(z_bf[(long)s3 * 64 + lane]), a3);
        }
    }
    const float acc = (a0 + a1) + (a2 + a3);
    __builtin_nontemporal_store((end > beg) ? acc / den : 0.f,
                                h + (long)n * 64 + lane);
}

extern "C" void kernel_launch(void* const* d_in, const int* in_sizes, int n_in,
                              void* d_out, int out_size, void* d_ws, size_t ws_size,
                              hipStream_t stream) {
    const float* nfeats = (const float*)d_in[0];
    const float* efeats = (const float*)d_in[1];
    const int*   src    = (const int*)d_in[2];
    const int*   dst    = (const int*)d_in[3];
    const float* W_fc   = (const float*)d_in[4];
    const float* W_edge = (const float*)d_in[5];
    const float* b_edge = (const float*)d_in[6];
    const float* w_coef = (const float*)d_in[7];

    const int  N = in_sizes[0] / 128;   // 50000
    const long E = in_sizes[2];         // 1600000
    const int  nb = (N + 1023) / 1024;  // 49
    const int  ntiles = N / 16;         // 3125

    float* h    = (float*)d_out;                 // [N,64]
    float* feat = (float*)d_out + (long)N * 64;  // [E,64]

    unsigned short* z_bf   = (unsigned short*)d_ws;        // N*64 bf16
    unsigned short* p_bf   = z_bf + (long)N * 64;          // N*64 bf16
    unsigned short* q_bf   = p_bf + (long)N * 64;          // N*64 bf16
    unsigned short* wp_bf  = q_bf + (long)N * 64;          // 64*128
    unsigned short* wq_bf  = wp_bf + 64 * 128;             // 64*128
    float*          exbuf  = (float*)(wq_bf + 64 * 128);   // E
    int*            deg    = (int*)(exbuf + E);            // N
    int*            rank   = deg + N;                      // E
    int*            off    = rank + E;                     // N+2 (8B-align pairs)
    i32x2*          pairs  = (i32x2*)(off + N + 2);        // E
    int*            bsum   = (int*)(pairs + E);            // 64
    int*            bpre   = bsum + 64;                    // 64

    k0_wpq<<<32, 256, 0, stream>>>(W_edge, W_fc, wp_bf, wq_bf);
    k12_node<<<(ntiles + 3) / 4, 256, 0, stream>>>(nfeats, W_fc, wp_bf, wq_bf,
                                                   b_edge, z_bf, p_bf, q_bf,
                                                   deg, ntiles);
    k3_edges<<<(int)(E / 512), 256, 0, stream>>>(efeats, src, dst, W_edge, w_coef,
                                                 p_bf, q_bf, feat, exbuf, deg, rank);
    k_scan1<<<nb, 256, 0, stream>>>(deg, bsum, N);
    k_scan2<<<1, 64, 0, stream>>>(bsum, bpre, off, nb, N);
    k_scan3<<<nb, 256, 0, stream>>>(deg, bpre, off, N);
    k_scatter<<<(int)((E + 255) / 256), 256, 0, stream>>>(src, dst, exbuf, off,
                                                          rank, pairs, E);
    k5_aggregate<<<(N + 3) / 4, 256, 0, stream>>>(off, pairs, z_bf, h, N);
}

// Round 19
// 339.052 us; speedup vs baseline: 1.3888x; 1.0148x over previous
//
#include <hip/hip_runtime.h>
#include <hip/hip_bf16.h>

// GAT layer: N=50000 nodes, E=1.6M edges, DIN_N=128, DIN_E=64, DOUT_N=DOUT_E=64.
//   Wp = W1@W_fc, Wq = W3@W_fc                           (k0, 64x128 each, bf16)
//   z = x@W_fc.T; p = x@Wp.T + b; q = x@Wq.T             (k12, one MFMA GEMM, bf16 out;
//                                                         also zeroes deg)
//   feat[e] = lrelu([ef | p[src] | q[dst]] @ [W2; I; I])  (K3, K=192 MFMA,
//                         identity-B frags do the A->C transpose of p/q)
//   a = lrelu(lrelu(feat . wc)); ex = exp(a);
//   rank[e] = deg[dst]++  (atomic return value)           (K3)
//   off = exscan(deg)  (scan1/2/3)
//   pairs[off[dst]+rank[e]] = {src, ex}                   (scatter, NO atomics)
//   h[n] = sum(ex * z_bf[src]) / sum(ex)                  (K5, wave/node)
// Segment-max skipped: a is O(+-4) so exp cannot overflow; alpha identical.
// R18->R19: k3 at 512 threads/block (8 waves x 4 tiles): W2f (8KB) amortized
// over 8 waves -> 40KB/block, 4 blocks/CU = 32 waves/CU occupancy cap (was
// 24), LDS/wave 6->5KB. Per-wave body SMALLER than R18 (4 tiles, single
// sAll/dAll). Same vmcnt(16) discipline. launch_bounds(512,4) = proven
// 128-reg cap.

typedef __attribute__((ext_vector_type(8))) short short8;
typedef __attribute__((ext_vector_type(4))) float f32x4;
typedef __attribute__((ext_vector_type(2))) int i32x2;

__device__ __forceinline__ short bf1(float f) {
    union { __hip_bfloat16 h; short s; } u;
    u.h = __float2bfloat16(f);          // compiler emits v_cvt_pk_bf16_f32 pairs
    return u.s;
}

__device__ __forceinline__ float bf2f(unsigned short u) {
    union { unsigned v; float f; } w; w.v = ((unsigned)u) << 16; return w.f;
}

__device__ __forceinline__ short8 pack8(f32x4 a, f32x4 b) {
    short8 r;
    r[0] = bf1(a[0]); r[1] = bf1(a[1]); r[2] = bf1(a[2]); r[3] = bf1(a[3]);
    r[4] = bf1(b[0]); r[5] = bf1(b[1]); r[6] = bf1(b[2]); r[7] = bf1(b[3]);
    return r;
}

__device__ __forceinline__ f32x4 ntld4(const float* p) {
    return __builtin_nontemporal_load((const f32x4*)p);
}

__device__ __forceinline__ f32x4 ld4(const float* p) {
    return *(const f32x4*)p;
}

#define MFMA16(A, B, C) __builtin_amdgcn_mfma_f32_16x16x32_bf16((A), (B), (C), 0, 0, 0)

// ---------------- k0: Wp = W1@W_fc, Wq = W3@W_fc (bf16 out) ----------------
__global__ __launch_bounds__(256) void k0_wpq(
    const float* __restrict__ W_edge, const float* __restrict__ W_fc,
    unsigned short* __restrict__ wp_bf, unsigned short* __restrict__ wq_bf)
{
    const int i = blockIdx.x * 256 + threadIdx.x;   // 0..8191
    if (i >= 64 * 128) return;
    const int c = i >> 7, k = i & 127;
    float sp = 0.f, sq = 0.f;
    for (int j = 0; j < 64; ++j) {
        const float f = W_fc[j * 128 + k];
        sp += W_edge[c * 192 + j] * f;
        sq += W_edge[c * 192 + 128 + j] * f;
    }
    wp_bf[i] = (unsigned short)bf1(sp);
    wq_bf[i] = (unsigned short)bf1(sq);
}

// ---------------- k12: z/p/q = x @ {W_fc,Wp,Wq}.T via MFMA; deg = 0 ---------
// C/D layout: col = lane&15, row = (lane>>4)*4 + reg (m89-verified).
__global__ __launch_bounds__(256) void k12_node(
    const float* __restrict__ nfeats, const float* __restrict__ W_fc,
    const unsigned short* __restrict__ wp_bf, const unsigned short* __restrict__ wq_bf,
    const float* __restrict__ b_edge,
    unsigned short* __restrict__ z_bf, unsigned short* __restrict__ p_bf,
    unsigned short* __restrict__ q_bf, int* __restrict__ deg, int ntiles)
{
    const int lane = threadIdx.x & 63;
    const int wave = threadIdx.x >> 6;
    const int l15 = lane & 15, g = lane >> 4;
    const int ti = blockIdx.x * 4 + wave;
    if (ti >= ntiles) return;
    const int n0 = ti * 16;

    if (lane < 16) deg[n0 + lane] = 0;   // replaces the memset launch

    // A fragments: 16 nodes x K=128 of nfeats (bf16)
    const float* xp = nfeats + (long)(n0 + l15) * 128 + g * 8;
    short8 Ax[4];
#pragma unroll
    for (int kt = 0; kt < 4; ++kt)
        Ax[kt] = pack8(ntld4(xp + kt * 32), ntld4(xp + kt * 32 + 4));

#pragma unroll
    for (int t = 0; t < 4; ++t) {
        const int col = t * 16 + l15;
        f32x4 az = (f32x4){0.f, 0.f, 0.f, 0.f};
        f32x4 ap = az, aq = az;
#pragma unroll
        for (int kt = 0; kt < 4; ++kt) {
            const float* bz = W_fc + (long)col * 128 + kt * 32 + g * 8;
            az = MFMA16(Ax[kt], pack8(ld4(bz), ld4(bz + 4)), az);
            const short8 bp = *(const short8*)(wp_bf + (long)col * 128 + kt * 32 + g * 8);
            ap = MFMA16(Ax[kt], bp, ap);
            const short8 bq = *(const short8*)(wq_bf + (long)col * 128 + kt * 32 + g * 8);
            aq = MFMA16(Ax[kt], bq, aq);
        }
        const float bias = b_edge[col];
#pragma unroll
        for (int r = 0; r < 4; ++r) {
            const long row = n0 + g * 4 + r;
            z_bf[row * 64 + col] = (unsigned short)bf1(az[r]);
            p_bf[row * 64 + col] = (unsigned short)bf1(ap[r] + bias);
            q_bf[row * 64 + col] = (unsigned short)bf1(aq[r]);
        }
    }
}

// ---------------- K3: per-edge K=192 MFMA + logits + deg/rank ----------------
// 512-thread blocks: 8 waves x 4 tiles x 16 edges = 512 edges/block.
// ef staged via global_load_lds into a SINGLE 4KB buffer per wave; W2f (8KB)
// shared by 8 waves -> 40KB/block -> 4 blocks/CU (32 waves/CU cap).
// LDS granule (16B) L of a 4KB tile holds GLOBAL granule
//   (L&~15) | ((L&15) ^ ((L>>4)&7))  -- source-side XOR swizzle so the
// stride-256B ds_read_b128 spreads across 8 bank groups.
// Per-tile: vmcnt(16) waits the stage issued last tile (19 newer vmem ops:
// 16 feat stores + exbuf + rank + atomicAdd; margin 3). lgkmcnt(0) orders
// this tile's ds_reads before the same-buffer restage.
// C/D layout (m89-verified): col = lane&15, row = (lane>>4)*4 + reg.
#define LOAD_PQ(T, PQ) {                                                    \
    const int sE_ = __shfl(sAll, (T) * 16 + l15, 64);                       \
    const int dE_ = __shfl(dAll, (T) * 16 + l15, 64);                       \
    const unsigned short* pp_ = p_bf + (long)sE_ * 64 + g * 8;              \
    PQ[0] = *(const short8*)pp_;                                            \
    PQ[1] = *(const short8*)(pp_ + 32);                                     \
    const unsigned short* qp_ = q_bf + (long)dE_ * 64 + g * 8;              \
    PQ[2] = *(const short8*)qp_;                                            \
    PQ[3] = *(const short8*)(qp_ + 32);                                     \
}

#define STAGE_EF(T) {                                                       \
    const float* gs_ = efeats + (wbase + (T) * 16) * 64;                    \
    _Pragma("unroll")                                                       \
    for (int i_ = 0; i_ < 4; ++i_) {                                        \
        const int L_ = i_ * 64 + lane;                                      \
        const int G_ = (L_ & ~15) | ((L_ & 15) ^ ((L_ >> 4) & 7));          \
        __builtin_amdgcn_global_load_lds(                                   \
            (const __attribute__((address_space(1))) unsigned int*)(gs_ + G_ * 4), \
            (__attribute__((address_space(3))) unsigned int*)(&efb[wave][i_ * 256]), \
            16, 0, 0);                                                      \
    }                                                                       \
}

#define EF_READ(E0, E1, E2, E3) {                                           \
    const float* eb2_ = &efb[wave][0];                                      \
    const int ro_ = l15 * 64, sx_ = l15 & 7;                                \
    E0 = *(const f32x4*)(eb2_ + ro_ + (((2 * g    ) ^ sx_) << 2));          \
    E1 = *(const f32x4*)(eb2_ + ro_ + (((2 * g + 1) ^ sx_) << 2));          \
    E2 = *(const f32x4*)(eb2_ + ro_ + (((2 * g + 8) ^ sx_) << 2));          \
    E3 = *(const f32x4*)(eb2_ + ro_ + (((2 * g + 9) ^ sx_) << 2));          \
}

#define VMW asm volatile("s_waitcnt vmcnt(16)" ::: "memory");

#define DO_TILE(T, PQ, DOWAIT, DOPQ, DOSTAGE) {                             \
    const long eb_ = wbase + (T) * 16;                                      \
    DOWAIT                                                                  \
    f32x4 e0_, e1_, e2_, e3_;                                               \
    EF_READ(e0_, e1_, e2_, e3_);                                            \
    DOPQ                                                                    \
    asm volatile("s_waitcnt lgkmcnt(0)" ::: "memory");                      \
    DOSTAGE                                                                 \
    f32x4 acc_[4];                                                          \
    _Pragma("unroll")                                                       \
    for (int t = 0; t < 4; ++t) acc_[t] = (f32x4){0.f, 0.f, 0.f, 0.f};      \
    acc_[0] = MFMA16(PQ[0], IdA, acc_[0]);                                  \
    acc_[1] = MFMA16(PQ[0], IdB, acc_[1]);                                  \
    acc_[2] = MFMA16(PQ[1], IdA, acc_[2]);                                  \
    acc_[3] = MFMA16(PQ[1], IdB, acc_[3]);                                  \
    acc_[0] = MFMA16(PQ[2], IdA, acc_[0]);                                  \
    acc_[1] = MFMA16(PQ[2], IdB, acc_[1]);                                  \
    acc_[2] = MFMA16(PQ[3], IdA, acc_[2]);                                  \
    acc_[3] = MFMA16(PQ[3], IdB, acc_[3]);                                  \
    short8 Aef0_ = pack8(e0_, e1_), Aef1_ = pack8(e2_, e3_);                \
    _Pragma("unroll")                                                       \
    for (int t = 0; t < 4; ++t) {                                           \
        acc_[t] = MFMA16(Aef0_, W2f[t * 64 + lane], acc_[t]);               \
        acc_[t] = MFMA16(Aef1_, W2f[(4 + t) * 64 + lane], acc_[t]);         \
    }                                                                       \
    float myex_ = 0.f;                                                      \
    _Pragma("unroll")                                                       \
    for (int r = 0; r < 4; ++r) {                                           \
        float s_ = 0.f;                                                     \
        _Pragma("unroll")                                                   \
        for (int t = 0; t < 4; ++t) {                                       \
            float v_ = acc_[t][r];                                          \
            v_ = (v_ >= 0.f) ? v_ : 0.01f * v_;                             \
            __builtin_nontemporal_store(v_,                                 \
                feat_out + (eb_ + g * 4 + r) * 64 + t * 16 + l15);          \
            s_ += v_ * wc[t];                                               \
        }                                                                   \
        s_ += __shfl_xor(s_, 1, 16);                                        \
        s_ += __shfl_xor(s_, 2, 16);                                        \
        s_ += __shfl_xor(s_, 4, 16);                                        \
        s_ += __shfl_xor(s_, 8, 16);                                        \
        s_ = (s_ >= 0.f) ? s_ : 0.01f * s_;                                 \
        s_ = (s_ >= 0.f) ? s_ : 0.01f * s_;                                 \
        const float ex_ = __expf(s_);                                       \
        if (l15 == r) myex_ = ex_;                                          \
    }                                                                       \
    const int dmine_ = __shfl(dAll, (T) * 16 + g * 4 + (l15 & 3), 64);      \
    if (l15 < 4) {                                                          \
        exbuf[eb_ + g * 4 + l15] = myex_;                                   \
        rank[eb_ + g * 4 + l15] = atomicAdd(&deg[dmine_], 1);               \
    }                                                                       \
}

__global__ __launch_bounds__(512, 4) void k3_edges(
    const float* __restrict__ efeats, const int* __restrict__ src,
    const int* __restrict__ dst, const float* __restrict__ W_edge,
    const float* __restrict__ w_coef, const unsigned short* __restrict__ p_bf,
    const unsigned short* __restrict__ q_bf, float* __restrict__ feat_out,
    float* __restrict__ exbuf, int* __restrict__ deg, int* __restrict__ rank)
{
    __shared__ short8 W2f[512];     // pre-packed W2 B-frags, 8KB (shared by 8 waves)
    __shared__ float efb[8][1024];  // [wave][4KB ef tile], 32KB -> 40KB total

    const int tid = threadIdx.x;
    const int lane = tid & 63;
    const int wave = tid >> 6;                    // 0..7
    const int l15 = lane & 15, g = lane >> 4;
    const long wbase = ((long)blockIdx.x * 8 + wave) * 64;   // 64 edges/wave

    // stage tile 0 (drained by the __syncthreads below)
    STAGE_EF(0);
    const int sAll = src[wbase + lane];
    const int dAll = dst[wbase + lane];

    // fill W2 fragment LDS: one frag per thread (512 threads = 512 frags)
    {
        const int fi = tid;
        const int s = fi >> 6, l = fi & 63;
        const int col = (s & 3) * 16 + (l & 15);
        const int gg = l >> 4, kt = s >> 2;
        const float* wp = W_edge + col * 192 + 64 + kt * 32 + gg * 8;
        W2f[fi] = pack8(ld4(wp), ld4(wp + 4));
    }

    float wc[4];
#pragma unroll
    for (int t = 0; t < 4; ++t) wc[t] = w_coef[t * 16 + l15];

    // identity B-fragments: one-hot at kc == col (mod 32 block)
    const short one = (short)0x3F80;   // bf16 1.0
    short8 IdA, IdB;
#pragma unroll
    for (int jj = 0; jj < 8; ++jj) {
        IdA[jj] = (l15 == g * 8 + jj) ? one : (short)0;        // cols 0..15 / 32..47
        IdB[jj] = (16 + l15 == g * 8 + jj) ? one : (short)0;   // cols 16..31 / 48..63
    }

    short8 pqA[4], pqB[4];
    LOAD_PQ(0, pqA);
    __syncthreads();   // W2f visible; vmcnt(0)+lgkmcnt(0) drain: tile 0 staged

    DO_TILE(0, pqA, ,    { LOAD_PQ(1, pqB); }, { STAGE_EF(1); });
    DO_TILE(1, pqB, VMW, { LOAD_PQ(2, pqA); }, { STAGE_EF(2); });
    DO_TILE(2, pqA, VMW, { LOAD_PQ(3, pqB); }, { STAGE_EF(3); });
    DO_TILE(3, pqB, VMW, , );
}

// ---------------- scan1: per-block (1024 elems) totals ----------------
__global__ __launch_bounds__(256) void k_scan1(
    const int* __restrict__ deg, int* __restrict__ bsum, int N)
{
    __shared__ int ws4[4];
    const int tid = threadIdx.x, lane = tid & 63, wave = tid >> 6;
    const int i0 = blockIdx.x * 1024 + tid * 4;
    int s = 0;
#pragma unroll
    for (int jj = 0; jj < 4; ++jj) {
        const int i = i0 + jj;
        if (i < N) s += deg[i];
    }
#pragma unroll
    for (int d = 1; d < 64; d <<= 1) s += __shfl_xor(s, d, 64);
    if (lane == 0) ws4[wave] = s;
    __syncthreads();
    if (tid == 0) bsum[blockIdx.x] = ws4[0] + ws4[1] + ws4[2] + ws4[3];
}

// ---------------- scan2: scan of block totals (<=64 blocks) ----------------
__global__ __launch_bounds__(64) void k_scan2(
    const int* __restrict__ bsum, int* __restrict__ bpre,
    int* __restrict__ off, int nb, int N)
{
    const int t = threadIdx.x;
    const int v = (t < nb) ? bsum[t] : 0;
    int x = v;
#pragma unroll
    for (int d = 1; d < 64; d <<= 1) {
        int y = __shfl_up(x, d, 64);
        if (t >= d) x += y;
    }
    if (t < nb) bpre[t] = x - v;
    if (t == 63) off[N] = x;   // grand total == E
}

// ---------------- scan3: write off[i] ----------------
__global__ __launch_bounds__(256) void k_scan3(
    const int* __restrict__ deg, const int* __restrict__ bpre,
    int* __restrict__ off, int N)
{
    __shared__ int ws4[4];
    const int tid = threadIdx.x, lane = tid & 63, wave = tid >> 6;
    const int i0 = blockIdx.x * 1024 + tid * 4;
    int v[4];
#pragma unroll
    for (int jj = 0; jj < 4; ++jj) {
        const int i = i0 + jj;
        v[jj] = (i < N) ? deg[i] : 0;
    }
    const int s = v[0] + v[1] + v[2] + v[3];
    int x = s;
#pragma unroll
    for (int d = 1; d < 64; d <<= 1) {
        int y = __shfl_up(x, d, 64);
        if (lane >= d) x += y;
    }
    if (lane == 63) ws4[wave] = x;
    __syncthreads();
    int wpre = 0;
#pragma unroll
    for (int w = 0; w < 4; ++w) if (w < wave) wpre += ws4[w];
    int run = bpre[blockIdx.x] + wpre + (x - s);
#pragma unroll
    for (int jj = 0; jj < 4; ++jj) {
        const int i = i0 + jj;
        if (i < N) off[i] = run;
        run += v[jj];
    }
}

// ---------------- scatter (atomic-free): pairs[off[d]+rank[e]] = {src, ex} ----
__global__ __launch_bounds__(256) void k_scatter(
    const int* __restrict__ src, const int* __restrict__ dst,
    const float* __restrict__ exbuf, const int* __restrict__ off,
    const int* __restrict__ rank, i32x2* __restrict__ pairs, long E)
{
    const long e = (long)blockIdx.x * 256 + threadIdx.x;
    if (e >= E) return;
    const int d = dst[e];
    const int pos = off[d] + rank[e];
    i32x2 pr;
    pr[0] = src[e];
    pr[1] = __float_as_int(exbuf[e]);
    pairs[pos] = pr;
}

// ---------------- K5: h[n] = sum(ex*z[src]) / sum(ex) ----------------
// one wave per node; lane = channel; z gathered as bf16 (128B rows).
__global__ __launch_bounds__(256) void k5_aggregate(
    const int* __restrict__ off, const i32x2* __restrict__ pairs,
    const unsigned short* __restrict__ z_bf, float* __restrict__ h, int N)
{
    const int wave = threadIdx.x >> 6, lane = threadIdx.x & 63;
    const int n = blockIdx.x * 4 + wave;
    if (n >= N) return;
    const int beg = off[n], end = off[n + 1];
    float den = 0.f;
    float a0 = 0.f, a1 = 0.f, a2 = 0.f, a3 = 0.f;
    for (int base = beg; base < end; base += 64) {
        const int rem = end - base;
        i32x2 pr = (i32x2){0, 0};
        if (lane < rem) pr = __builtin_nontemporal_load(&pairs[base + lane]);
        const float ex = __int_as_float(pr[1]);
        float t = ex;
#pragma unroll
        for (int d = 1; d < 64; d <<= 1) t += __shfl_xor(t, d, 64);
        den += t;
        const int cnt = rem < 64 ? rem : 64;
        const int cnt4 = (cnt + 3) & ~3;
        for (int j = 0; j < cnt4; j += 4) {
            const int s0 = __shfl(pr[0], j, 64);
            const int s1 = __shfl(pr[0], j + 1, 64);
            const int s2 = __shfl(pr[0], j + 2, 64);
            const int s3 = __shfl(pr[0], j + 3, 64);
            const float e0 = __shfl(ex, j, 64);
            const float e1 = __shfl(ex, j + 1, 64);
            const float e2 = __shfl(ex, j + 2, 64);
            const float e3 = __shfl(ex, j + 3, 64);
            a0 = fmaf(e0, bf2f(z_bf[(long)s0 * 64 + lane]), a0);
            a1 = fmaf(e1, bf2f(z_bf[(long)s1 * 64 + lane]), a1);
            a2 = fmaf(e2, bf2f(z_bf[(long)s2 * 64 + lane]), a2);
            a3 = fmaf(e3, bf2f(z_bf[(long)s3 * 64 + lane]), a3);
        }
    }
    const float acc = (a0 + a1) + (a2 + a3);
    __builtin_nontemporal_store((end > beg) ? acc / den : 0.f,
                                h + (long)n * 64 + lane);
}

extern "C" void kernel_launch(void* const* d_in, const int* in_sizes, int n_in,
                              void* d_out, int out_size, void* d_ws, size_t ws_size,
                              hipStream_t stream) {
    const float* nfeats = (const float*)d_in[0];
    const float* efeats = (const float*)d_in[1];
    const int*   src    = (const int*)d_in[2];
    const int*   dst    = (const int*)d_in[3];
    const float* W_fc   = (const float*)d_in[4];
    const float* W_edge = (const float*)d_in[5];
    const float* b_edge = (const float*)d_in[6];
    const float* w_coef = (const float*)d_in[7];

    const int  N = in_sizes[0] / 128;   // 50000
    const long E = in_sizes[2];         // 1600000
    const int  nb = (N + 1023) / 1024;  // 49
    const int  ntiles = N / 16;         // 3125

    float* h    = (float*)d_out;                 // [N,64]
    float* feat = (float*)d_out + (long)N * 64;  // [E,64]

    unsigned short* z_bf   = (unsigned short*)d_ws;        // N*64 bf16
    unsigned short* p_bf   = z_bf + (long)N * 64;          // N*64 bf16
    unsigned short* q_bf   = p_bf + (long)N * 64;          // N*64 bf16
    unsigned short* wp_bf  = q_bf + (long)N * 64;          // 64*128
    unsigned short* wq_bf  = wp_bf + 64 * 128;             // 64*128
    float*          exbuf  = (float*)(wq_bf + 64 * 128);   // E
    int*            deg    = (int*)(exbuf + E);            // N
    int*            rank   = deg + N;                      // E
    int*            off    = rank + E;                     // N+2 (8B-align pairs)
    i32x2*          pairs  = (i32x2*)(off + N + 2);        // E
    int*            bsum   = (int*)(pairs + E);            // 64
    int*            bpre   = bsum + 64;                    // 64

    k0_wpq<<<32, 256, 0, stream>>>(W_edge, W_fc, wp_bf, wq_bf);
    k12_node<<<(ntiles + 3) / 4, 256, 0, stream>>>(nfeats, W_fc, wp_bf, wq_bf,
                                                   b_edge, z_bf, p_bf, q_bf,
                                                   deg, ntiles);
    k3_edges<<<(int)(E / 512), 512, 0, stream>>>(efeats, src, dst, W_edge, w_coef,
                                                 p_bf, q_bf, feat, exbuf, deg, rank);
    k_scan1<<<nb, 256, 0, stream>>>(deg, bsum, N);
    k_scan2<<<1, 64, 0, stream>>>(bsum, bpre, off, nb, N);
    k_scan3<<<nb, 256, 0, stream>>>(deg, bpre, off, N);
    k_scatter<<<(int)((E + 255) / 256), 256, 0, stream>>>(src, dst, exbuf, off,
                                                          rank, pairs, E);
    k5_aggregate<<<(N + 3) / 4, 256, 0, stream>>>(off, pairs, z_bf, h, N);
}